// Round 7
// baseline (122.464 us; speedup 1.0000x reference)
//
#include <hip/hip_runtime.h>
#include <stdint.h>

// DiscreteMarkovDynamics: 5-step Markov jump sim, B=32, L=4096, V=512.
// R1: table precompute + wave-per-position categorical -> 1024 us.
// R2: provable-reject skip (u >= pthr[s] => categorical dead code) -> 250 us.
// R3: split/parallel builds, LDS pthr, PPW=8 -> 125 us.
// R4: fused wide build; ballot candidate scan -> 121 us (markov 52).
// R5: zoned work-steal REGRESSED: 16 counters in ONE cacheline -> every pop
//     ping-pongs cross-XCD (~43 cyc serialized) -> 293 us.
// R6: 2-wave blocks + ILP categorical -> 116 us (markov 45).
// R7: static 2 chunks/wave REGRESSED markov to 53 (no backfill).
// R8: 2048x256, 8 chunks/block via LDS counter -> 109 us (markov ~45).
// R9/R10: two-phase LDS queue -> 3 contentless infra exceptions, unresolved.
// R11: CONTROL R8 verbatim -> PASSED 108.8, counters identical.
// R12: 2x per-block pool -> NULL. R13: candidate pairing + slim reduce ->
//     NULL. Four shapes all at markov ~45 us => the invariant is PER-CU
//     total work: blocks are statically bound to chunks, so the hottest CU
//     (~1.4-1.8x mean categoricals; accepts bias toward high-pthr states ->
//     re-arm chains -> overdispersion) sets the duration. Within-CU
//     rebalancing (R12) and per-wave latency (R13) can't touch it.
// R14: cross-CU balancing done right (R5's failure mode removed):
//     8 partition counters in SEPARATE 256B-spaced cachelines; partition =
//     blockIdx.x & 7 (round-robin XCD heuristic -> single-XCD counter
//     traffic, no ping-pong; correctness independent of mapping: bijection
//     chunk = c*8 + part, 1024 resident waves per partition drain it).
//     Waves pop chunks at chunk granularity from their partition counter.
//     build_table zeroes counters (stream-ordered, graph-safe). Inner loop
//     is R8's proven body byte-for-byte; LDS counter removed.

#define VOCAB  512
#define EMB    256
#define HID    64
#define NPOS   (32 * 4096)   // B*L = 131072
#define STEPS  5
#define PPW    8             // positions per chunk; PPW*STEPS=40 <= 64 lanes
#define CHUNKS (NPOS / PPW)  // 16384
#define MBLK   2048          // markov blocks (exact residency at 256 thr)
#define NPART  8             // work partitions (~XCDs)
#define PCHUNK (CHUNKS / NPART)  // 2048 chunks per partition
#define CTR_STRIDE 64        // ints between counters = 256 B (no false share)

// Exact mirror of jax._src.prng.threefry2x32 (20 rounds).
__host__ __device__ __forceinline__ void tf2x32(uint32_t k0, uint32_t k1,
                                                uint32_t x0, uint32_t x1,
                                                uint32_t& o0, uint32_t& o1) {
  uint32_t ks2 = k0 ^ k1 ^ 0x1BD11BDAu;
  x0 += k0; x1 += k1;
#define TFR(r) { x0 += x1; x1 = (x1 << (r)) | (x1 >> (32 - (r))); x1 ^= x0; }
  TFR(13) TFR(15) TFR(26) TFR(6)
  x0 += k1;  x1 += ks2 + 1u;
  TFR(17) TFR(29) TFR(16) TFR(24)
  x0 += ks2; x1 += k0 + 2u;
  TFR(13) TFR(15) TFR(26) TFR(6)
  x0 += k0;  x1 += k1 + 3u;
  TFR(17) TFR(29) TFR(16) TFR(24)
  x0 += k1;  x1 += ks2 + 4u;
  TFR(13) TFR(15) TFR(26) TFR(6)
  x0 += ks2; x1 += k0 + 5u;
#undef TFR
  o0 = x0; o1 = x1;
}

struct Keys {
  uint32_t k1a[STEPS], k1b[STEPS];  // categorical (gumbel) keys per step
  uint32_t k2a[STEPS], k2b[STEPS];  // accept-uniform keys per step
};

// Fused table build (R8 body + counter zeroing; a few us in-graph).
__global__ __launch_bounds__(512)
void build_table(const float* __restrict__ emb,
                 const float* __restrict__ W1,
                 const float* __restrict__ b1,
                 const float* __restrict__ W2,
                 const float* __restrict__ b2,
                 float* __restrict__ I,
                 float* __restrict__ pthr,
                 int* __restrict__ cnt) {
  const int s   = blockIdx.x;
  const int tid = threadIdx.x;
  __shared__ double part[8][HID];
  __shared__ double hd[HID];
  __shared__ float  redmax[8];

  // Zero the markov partition counters (stream order guarantees visibility).
  if (s < NPART && tid == 0) cnt[s * CTR_STRIDE] = 0;

  const int hid = tid & (HID - 1);
  const int kq  = tid >> 6;               // 0..7, k = kq + 8*i
  const float* e = emb + s * EMB;
  double acc = 0.0;
#pragma unroll
  for (int ib = 0; ib < 32; ib += 16) {   // two 16-wide batches
    float ev[16], wv[16];
#pragma unroll
    for (int i = 0; i < 16; ++i) {        // 32 loads issued together
      const int k = kq + 8 * (ib + i);
      ev[i] = e[k];
      wv[i] = W1[k * HID + hid];
    }
#pragma unroll
    for (int i = 0; i < 16; ++i)          // same order as R4's k-loop
      acc += (double)ev[i] * (double)wv[i];
  }
  part[kq][hid] = acc;
  __syncthreads();
  if (kq == 0) {
    const double a = ((part[0][hid] + part[1][hid]) + (part[2][hid] + part[3][hid]))
                   + ((part[4][hid] + part[5][hid]) + (part[6][hid] + part[7][hid]));
    const float m = (float)a + b1[hid];
    hd[hid] = (double)(m > 0.0f ? m : 0.0f);   // relu
  }
  __syncthreads();

  double acc2 = 0.0;
#pragma unroll
  for (int kb = 0; kb < HID; kb += 16) {  // four 16-wide batches
    float wv[16];
#pragma unroll
    for (int i = 0; i < 16; ++i)
      wv[i] = W2[(kb + i) * VOCAB + tid]; // coalesced, 16 in flight
#pragma unroll
    for (int i = 0; i < 16; ++i)          // same serial order as before
      acc2 += hd[kb + i] * (double)wv[i];
  }
  const float val = (float)acc2 + b2[tid];
  I[s * VOCAB + tid] = val;

  float lmax = val;                        // max is order-insensitive
  for (int off = 32; off > 0; off >>= 1)
    lmax = fmaxf(lmax, __shfl_xor(lmax, off, 64));
  if ((tid & 63) == 0) redmax[tid >> 6] = lmax;
  __syncthreads();
  if (tid == 0) {
    float m = redmax[0];
#pragma unroll
    for (int i = 1; i < 8; ++i) m = fmaxf(m, redmax[i]);
    const float z = (-m) * 0.01f;          // same chain as accept path
    pthr[s] = 1.0f - (float)exp((double)z);// monotone => safe reject bound
  }
}

// Markov kernel: 2048 blocks x 256 = exact full residency. Each wave pops
// chunks from its partition counter (blockIdx&7); partition p owns chunks
// {c*8+p} — device-wide dynamic balancing with single-XCD counter traffic.
// Inner loop byte-identical to R8/R11/R12.
__global__ __launch_bounds__(256)
void markov_kernel(const int* __restrict__ x_in,
                   const float* __restrict__ I,
                   const float* __restrict__ pthr,
                   int* __restrict__ x_out,
                   int* __restrict__ cnt,
                   Keys K) {
  const int lane = threadIdx.x & 63;
  const int qp = lane / 5;                 // lane q -> (position, step)
  const int qt = lane - qp * 5;
  const float TINYF = 1.17549435e-38f;

  const int prt = blockIdx.x & (NPART - 1);
  int* ctr = cnt + prt * CTR_STRIDE;

  for (;;) {
    int c = 0;
    if (lane == 0) c = atomicAdd(ctr, 1);            // device-scope, 1 line/XCD
    c = __shfl(c, 0, 64);                            // wave-uniform
    if (c >= PCHUNK) break;
    const int base = (c * NPART + prt) * PPW;        // bijection onto chunks

    // States (lanes 0..7), then per-position pthr, shfl'd to the test lanes.
    int scur = (lane < PPW) ? x_in[base + lane] : 0;
    const float pv = (lane < PPW) ? pthr[scur] : 0.0f;

    // Accept uniforms: lane q < 40 holds u for (p=q/5, t=q%5).
    float u40 = 0.0f;
    if (lane < PPW * STEPS) {
      uint32_t w0, w1;
      tf2x32(K.k2a[qt], K.k2b[qt], 0u, (uint32_t)(base + qp), w0, w1);
      u40 = __uint_as_float((((w0 ^ w1) >> 9) | 0x3f800000u)) - 1.0f;
    }

    // Candidate mask: u_q < pthr[s_p] (state fixed unless an accept occurs).
    const float pq = __shfl(pv, qp, 64);
    const bool cand = (lane < PPW * STEPS) && (u40 < pq);
    unsigned long long mask = __ballot(cand);

    while (mask) {
      const int q = (int)__builtin_ctzll(mask);   // wave-uniform
      mask &= mask - 1;
      const int p = q / 5;
      const int t = q - p * 5;
      const int s = __builtin_amdgcn_readfirstlane(__shfl(scur, p, 64));

      // --- Full categorical (bit-identical math; ILP-batched) ---
      const float* row = I + s * VOCAB;
      float rv[8];
#pragma unroll
      for (int j = 0; j < 8; ++j)               // prefetch row values (L2)
        rv[j] = row[lane + (j << 6)];

      const uint32_t fbase = ((uint32_t)(base + p) << 9) + (uint32_t)lane;
      uint32_t bits[8];
#pragma unroll
      for (int j = 0; j < 8; ++j) {             // 8 independent threefry
        uint32_t w0, w1;
        tf2x32(K.k1a[t], K.k1b[t], 0u, fbase + ((uint32_t)j << 6), w0, w1);
        bits[j] = w0 ^ w1;
      }

      float best = -__builtin_inff();
      float rbest = 0.0f;                        // row value of the winner
      int bidx = 0;
#pragma unroll
      for (int j = 0; j < 8; ++j) {             // 8 independent gumbel chains
        float ufv = __uint_as_float((bits[j] >> 9) | 0x3f800000u) - 1.0f;
        if (ufv == 0.0f) ufv = TINYF;
        const float g = -logf(-logf(ufv));
        const int v = lane + (j << 6);
        if (v != s) {
          const float val = rv[j] + g;
          if (val > best) { best = val; bidx = v; rbest = rv[j]; }
        }
      }
      for (int off = 32; off > 0; off >>= 1) {
        const float ob = __shfl_xor(best, off, 64);
        const int   oi = __shfl_xor(bidx, off, 64);
        const float orv = __shfl_xor(rbest, off, 64);
        if (ob > best || (ob == best && oi < bidx)) {
          best = ob; bidx = oi; rbest = orv;
        }
      }
      bidx = __builtin_amdgcn_readfirstlane(bidx);
      const float rate = rbest;                 // == row[bidx], no L2 load
      const float z = (-rate) * 0.01f;
      const float pacc = 1.0f - (float)exp((double)z);  // CR fp32 exp
      const float u = __shfl(u40, q, 64);
      if (u < pacc) {
        if (lane == p) scur = bidx;                     // accept jump
        // Re-evaluate this position's FUTURE steps under the new state.
        const unsigned long long fut =
            (((1ull << (p * 5 + 5)) - 1) & ~((1ull << (q + 1)) - 1));
        const float pnew = pthr[bidx];                  // scalar (bidx uniform)
        const unsigned long long nb = __ballot(u40 < pnew) & fut;
        mask = (mask & ~fut) | nb;
      }
    }
    if (lane < PPW) x_out[base + lane] = scur;
  }
}

extern "C" void kernel_launch(void* const* d_in, const int* in_sizes, int n_in,
                              void* d_out, int out_size, void* d_ws, size_t ws_size,
                              hipStream_t stream) {
  const int*   x   = (const int*)d_in[0];
  const float* emb = (const float*)d_in[1];
  const float* W1  = (const float*)d_in[2];
  const float* b1  = (const float*)d_in[3];
  const float* W2  = (const float*)d_in[4];
  const float* b2  = (const float*)d_in[5];
  float* I    = (float*)d_ws;                        // 1 MiB
  float* pthr = (float*)d_ws + VOCAB * VOCAB;        // +2 KiB
  int*   cnt  = (int*)((char*)d_ws + VOCAB * VOCAB * 4 + VOCAB * 4 + 256);
  int* out = (int*)d_out;

  // Host-side key derivation (partitionable scheme):
  //   key(42) = (0,42); split -> S_t = tf(key,(0,t)); (k1,k2) = tf(S_t,(0,j))
  Keys K;
  for (int t = 0; t < STEPS; ++t) {
    uint32_t Sa, Sb;
    tf2x32(0u, 42u, 0u, (uint32_t)t, Sa, Sb);
    tf2x32(Sa, Sb, 0u, 0u, K.k1a[t], K.k1b[t]);
    tf2x32(Sa, Sb, 0u, 1u, K.k2a[t], K.k2b[t]);
  }

  build_table<<<VOCAB, 512, 0, stream>>>(emb, W1, b1, W2, b2, I, pthr, cnt);
  markov_kernel<<<MBLK, 256, 0, stream>>>(x, I, pthr, out, cnt, K);
}

// Round 8
// 110.004 us; speedup vs baseline: 1.1133x; 1.1133x over previous
//
#include <hip/hip_runtime.h>
#include <stdint.h>

// DiscreteMarkovDynamics: 5-step Markov jump sim, B=32, L=4096, V=512.
// R1: table precompute + wave-per-position categorical -> 1024 us.
// R2: provable-reject skip (u >= pthr[s] => categorical dead code) -> 250 us.
// R3: split/parallel builds, LDS pthr, PPW=8 -> 125 us.
// R4: fused wide build; ballot candidate scan -> 121 us (markov 52).
// R5: zoned work-steal REGRESSED: 16 counters in ONE cacheline; calibration:
//     ~10 ns per serialized same-line device atomic (16k pops -> +172 us).
// R6: 2-wave blocks + ILP categorical -> 116 us (markov 45).
// R7: static 2 chunks/wave REGRESSED (exact residency, NO backfill).
// R8: 2048x256, 8 chunks/block via LDS counter -> 109 us (markov ~45).
// R9/R10: two-phase LDS queue -> 3 contentless infra exceptions, unresolved.
// R11: CONTROL R8 verbatim -> PASSED 108.8, counters identical.
// R12: 2x per-block pool -> NULL. R13: pairing + slim reduce -> NULL.
//     => limiter is per-CU total work (static chunk->CU binding).
// R14: 8-partition global-atomic popping REGRESSED (markov 62-67):
//     (a) ~3k pops/line x ~10ns serialization; (b) bijection c*8+prt split
//     every 64B x_out line across 2 XCDs -> WRITE 512->1280 KB. Global
//     atomics at chunk granularity are unaffordable; locality matters.
// R15: cross-CU balancing with ZERO atomics: the HW workgroup dispatcher.
//     8192 blocks x 128 thr (4x oversubscription), each wave owns ONE chunk,
//     blocks backfill CUs as they retire (the backfill R7 lacked). Pair
//     swizzle p=(b&7)*1024+(b>>3), chunks {2p,2p+1}: each 64B line of
//     x_in/x_out belongs to exactly one block (R14's amplification undone).
//     No LDS, no counters; inner math byte-identical to R8.

#define VOCAB  512
#define EMB    256
#define HID    64
#define NPOS   (32 * 4096)   // B*L = 131072
#define STEPS  5
#define PPW    8             // positions per chunk; PPW*STEPS=40 <= 64 lanes
#define CHUNKS (NPOS / PPW)  // 16384
#define MBLK   (CHUNKS / 2)  // 8192 blocks x 2 waves = 1 chunk per wave

// Exact mirror of jax._src.prng.threefry2x32 (20 rounds).
__host__ __device__ __forceinline__ void tf2x32(uint32_t k0, uint32_t k1,
                                                uint32_t x0, uint32_t x1,
                                                uint32_t& o0, uint32_t& o1) {
  uint32_t ks2 = k0 ^ k1 ^ 0x1BD11BDAu;
  x0 += k0; x1 += k1;
#define TFR(r) { x0 += x1; x1 = (x1 << (r)) | (x1 >> (32 - (r))); x1 ^= x0; }
  TFR(13) TFR(15) TFR(26) TFR(6)
  x0 += k1;  x1 += ks2 + 1u;
  TFR(17) TFR(29) TFR(16) TFR(24)
  x0 += ks2; x1 += k0 + 2u;
  TFR(13) TFR(15) TFR(26) TFR(6)
  x0 += k0;  x1 += k1 + 3u;
  TFR(17) TFR(29) TFR(16) TFR(24)
  x0 += k1;  x1 += ks2 + 4u;
  TFR(13) TFR(15) TFR(26) TFR(6)
  x0 += ks2; x1 += k0 + 5u;
#undef TFR
  o0 = x0; o1 = x1;
}

struct Keys {
  uint32_t k1a[STEPS], k1b[STEPS];  // categorical (gumbel) keys per step
  uint32_t k2a[STEPS], k2b[STEPS];  // accept-uniform keys per step
};

// Fused table build (unchanged R8 body; a few us in-graph).
__global__ __launch_bounds__(512)
void build_table(const float* __restrict__ emb,
                 const float* __restrict__ W1,
                 const float* __restrict__ b1,
                 const float* __restrict__ W2,
                 const float* __restrict__ b2,
                 float* __restrict__ I,
                 float* __restrict__ pthr) {
  const int s   = blockIdx.x;
  const int tid = threadIdx.x;
  __shared__ double part[8][HID];
  __shared__ double hd[HID];
  __shared__ float  redmax[8];

  const int hid = tid & (HID - 1);
  const int kq  = tid >> 6;               // 0..7, k = kq + 8*i
  const float* e = emb + s * EMB;
  double acc = 0.0;
#pragma unroll
  for (int ib = 0; ib < 32; ib += 16) {   // two 16-wide batches
    float ev[16], wv[16];
#pragma unroll
    for (int i = 0; i < 16; ++i) {        // 32 loads issued together
      const int k = kq + 8 * (ib + i);
      ev[i] = e[k];
      wv[i] = W1[k * HID + hid];
    }
#pragma unroll
    for (int i = 0; i < 16; ++i)          // same order as R4's k-loop
      acc += (double)ev[i] * (double)wv[i];
  }
  part[kq][hid] = acc;
  __syncthreads();
  if (kq == 0) {
    const double a = ((part[0][hid] + part[1][hid]) + (part[2][hid] + part[3][hid]))
                   + ((part[4][hid] + part[5][hid]) + (part[6][hid] + part[7][hid]));
    const float m = (float)a + b1[hid];
    hd[hid] = (double)(m > 0.0f ? m : 0.0f);   // relu
  }
  __syncthreads();

  double acc2 = 0.0;
#pragma unroll
  for (int kb = 0; kb < HID; kb += 16) {  // four 16-wide batches
    float wv[16];
#pragma unroll
    for (int i = 0; i < 16; ++i)
      wv[i] = W2[(kb + i) * VOCAB + tid]; // coalesced, 16 in flight
#pragma unroll
    for (int i = 0; i < 16; ++i)          // same serial order as before
      acc2 += hd[kb + i] * (double)wv[i];
  }
  const float val = (float)acc2 + b2[tid];
  I[s * VOCAB + tid] = val;

  float lmax = val;                        // max is order-insensitive
  for (int off = 32; off > 0; off >>= 1)
    lmax = fmaxf(lmax, __shfl_xor(lmax, off, 64));
  if ((tid & 63) == 0) redmax[tid >> 6] = lmax;
  __syncthreads();
  if (tid == 0) {
    float m = redmax[0];
#pragma unroll
    for (int i = 1; i < 8; ++i) m = fmaxf(m, redmax[i]);
    const float z = (-m) * 0.01f;          // same chain as accept path
    pthr[s] = 1.0f - (float)exp((double)z);// monotone => safe reject bound
  }
}

// Markov kernel R15: 8192 blocks x 128 thr, one chunk per wave, 4x
// oversubscription -> the HW dispatcher backfills CUs as blocks retire
// (zero-atomic cross-CU balancing). Pair swizzle keeps each 64B line of
// x_in/x_out within one block. Inner body byte-identical to R8.
__global__ __launch_bounds__(128)
void markov_kernel(const int* __restrict__ x_in,
                   const float* __restrict__ I,
                   const float* __restrict__ pthr,
                   int* __restrict__ x_out,
                   Keys K) {
  const int lane = threadIdx.x & 63;
  const int wid  = threadIdx.x >> 6;       // 0 or 1
  const int qp = lane / 5;                 // lane q -> (position, step)
  const int qt = lane - qp * 5;
  const float TINYF = 1.17549435e-38f;

  // Pair swizzle: blocks with equal (b&7) own a contiguous pair range.
  const int b = blockIdx.x;
  const int pair = (b & 7) * (MBLK / 8) + (b >> 3);
  const int base = (pair * 2 + wid) * PPW;

  // States (lanes 0..7), then per-position pthr, shfl'd to the test lanes.
  int scur = (lane < PPW) ? x_in[base + lane] : 0;
  const float pv = (lane < PPW) ? pthr[scur] : 0.0f;

  // Accept uniforms: lane q < 40 holds u for (p=q/5, t=q%5).
  float u40 = 0.0f;
  if (lane < PPW * STEPS) {
    uint32_t w0, w1;
    tf2x32(K.k2a[qt], K.k2b[qt], 0u, (uint32_t)(base + qp), w0, w1);
    u40 = __uint_as_float((((w0 ^ w1) >> 9) | 0x3f800000u)) - 1.0f;
  }

  // Candidate mask: u_q < pthr[s_p] (state fixed unless an accept occurs).
  const float pq = __shfl(pv, qp, 64);
  const bool cand = (lane < PPW * STEPS) && (u40 < pq);
  unsigned long long mask = __ballot(cand);

  while (mask) {
    const int q = (int)__builtin_ctzll(mask);   // wave-uniform
    mask &= mask - 1;
    const int p = q / 5;
    const int t = q - p * 5;
    const int s = __builtin_amdgcn_readfirstlane(__shfl(scur, p, 64));

    // --- Full categorical (bit-identical math; ILP-batched) ---
    const float* row = I + s * VOCAB;
    float rv[8];
#pragma unroll
    for (int j = 0; j < 8; ++j)               // prefetch row values (L2)
      rv[j] = row[lane + (j << 6)];

    const uint32_t fbase = ((uint32_t)(base + p) << 9) + (uint32_t)lane;
    uint32_t bits[8];
#pragma unroll
    for (int j = 0; j < 8; ++j) {             // 8 independent threefry
      uint32_t w0, w1;
      tf2x32(K.k1a[t], K.k1b[t], 0u, fbase + ((uint32_t)j << 6), w0, w1);
      bits[j] = w0 ^ w1;
    }

    float best = -__builtin_inff();
    float rbest = 0.0f;                        // row value of the winner
    int bidx = 0;
#pragma unroll
    for (int j = 0; j < 8; ++j) {             // 8 independent gumbel chains
      float ufv = __uint_as_float((bits[j] >> 9) | 0x3f800000u) - 1.0f;
      if (ufv == 0.0f) ufv = TINYF;
      const float g = -logf(-logf(ufv));
      const int v = lane + (j << 6);
      if (v != s) {
        const float val = rv[j] + g;
        if (val > best) { best = val; bidx = v; rbest = rv[j]; }
      }
    }
    for (int off = 32; off > 0; off >>= 1) {
      const float ob = __shfl_xor(best, off, 64);
      const int   oi = __shfl_xor(bidx, off, 64);
      const float orv = __shfl_xor(rbest, off, 64);
      if (ob > best || (ob == best && oi < bidx)) {
        best = ob; bidx = oi; rbest = orv;
      }
    }
    bidx = __builtin_amdgcn_readfirstlane(bidx);
    const float rate = rbest;                 // == row[bidx], no L2 load
    const float z = (-rate) * 0.01f;
    const float pacc = 1.0f - (float)exp((double)z);  // CR fp32 exp
    const float u = __shfl(u40, q, 64);
    if (u < pacc) {
      if (lane == p) scur = bidx;                     // accept jump
      // Re-evaluate this position's FUTURE steps under the new state.
      const unsigned long long fut =
          (((1ull << (p * 5 + 5)) - 1) & ~((1ull << (q + 1)) - 1));
      const float pnew = pthr[bidx];                  // scalar (bidx uniform)
      const unsigned long long nb = __ballot(u40 < pnew) & fut;
      mask = (mask & ~fut) | nb;
    }
  }
  if (lane < PPW) x_out[base + lane] = scur;
}

extern "C" void kernel_launch(void* const* d_in, const int* in_sizes, int n_in,
                              void* d_out, int out_size, void* d_ws, size_t ws_size,
                              hipStream_t stream) {
  const int*   x   = (const int*)d_in[0];
  const float* emb = (const float*)d_in[1];
  const float* W1  = (const float*)d_in[2];
  const float* b1  = (const float*)d_in[3];
  const float* W2  = (const float*)d_in[4];
  const float* b2  = (const float*)d_in[5];
  float* I    = (float*)d_ws;                        // 1 MiB
  float* pthr = (float*)d_ws + VOCAB * VOCAB;        // +2 KiB
  int* out = (int*)d_out;

  // Host-side key derivation (partitionable scheme):
  //   key(42) = (0,42); split -> S_t = tf(key,(0,t)); (k1,k2) = tf(S_t,(0,j))
  Keys K;
  for (int t = 0; t < STEPS; ++t) {
    uint32_t Sa, Sb;
    tf2x32(0u, 42u, 0u, (uint32_t)t, Sa, Sb);
    tf2x32(Sa, Sb, 0u, 0u, K.k1a[t], K.k1b[t]);
    tf2x32(Sa, Sb, 0u, 1u, K.k2a[t], K.k2b[t]);
  }

  build_table<<<VOCAB, 512, 0, stream>>>(emb, W1, b1, W2, b2, I, pthr);
  markov_kernel<<<MBLK, 128, 0, stream>>>(x, I, pthr, out, K);
}